// Round 3
// baseline (505.902 us; speedup 1.0000x reference)
//
#include <hip/hip_runtime.h>
#include <hip/hip_bf16.h>

#define HEADS  16
#define DHEAD  64
#define BATCH  4
#define SEQ    2048
#define DIM    1024
#define KVROWS 2112   // 2049 (null + SEQ) padded up to multiple of 64

typedef __hip_bfloat16 bf16;
typedef __attribute__((ext_vector_type(8))) short s8v;   // 8 x bf16 (4 VGPRs)
typedef __attribute__((ext_vector_type(4))) float f4v;   // MFMA accumulator

// ---------------------------------------------------------------------------
// fp32 -> bf16 bulk convert (8 elements/thread)
// ---------------------------------------------------------------------------
__global__ void convert_kernel(const float* __restrict__ in, bf16* __restrict__ out) {
  const size_t i = ((size_t)blockIdx.x * 256 + threadIdx.x) * 8;
  const float4 a = *(const float4*)&in[i];
  const float4 b = *(const float4*)&in[i + 4];
  bf16 v[8] = {__float2bfloat16(a.x), __float2bfloat16(a.y),
               __float2bfloat16(a.z), __float2bfloat16(a.w),
               __float2bfloat16(b.x), __float2bfloat16(b.y),
               __float2bfloat16(b.z), __float2bfloat16(b.w)};
  *(s8v*)&out[i] = *(s8v*)v;
}

// ---------------------------------------------------------------------------
// Transpose+convert: fp32 [R][C] -> bf16 [C][R]; R,C multiples of 32
// ---------------------------------------------------------------------------
__global__ void transpose_kernel(const float* __restrict__ in, bf16* __restrict__ out,
                                 int R, int C) {
  __shared__ bf16 tile[32][33];  // +1 pad: bank-conflict-free
  const int c0 = blockIdx.x * 32, r0 = blockIdx.y * 32;
  const int tx = threadIdx.x, ty = threadIdx.y;
#pragma unroll
  for (int i = 0; i < 32; i += 8)
    tile[ty + i][tx] = __float2bfloat16(in[(size_t)(r0 + ty + i) * C + c0 + tx]);
  __syncthreads();
#pragma unroll
  for (int i = 0; i < 32; i += 8)
    out[(size_t)(c0 + ty + i) * R + r0 + tx] = tile[tx][ty + i];
}

// ---------------------------------------------------------------------------
// GEMM: C = alpha * A[M][K] @ BT[N][K]^T  (bf16 in, fp32 acc, OT out)
// Tile BM=128, BN=64, BK=32; 4 waves, MFMA 16x16x32 bf16.
// kv_remap: output row m -> kvbuf row (m>>11)*KVROWS + (m&2047)+1.
// ---------------------------------------------------------------------------
template <typename OT>
__global__ __launch_bounds__(256) void gemm_bt_kernel(
    const bf16* __restrict__ A, const bf16* __restrict__ BT,
    OT* __restrict__ C, int K, int c_ld, float alpha, int kv_remap) {
  __shared__ bf16 As[128][32];  // 8 KB
  __shared__ bf16 Bs[64][32];   // 4 KB
  const int m0 = blockIdx.x * 128, n0 = blockIdx.y * 64;
  const int t = threadIdx.x;
  const int w = t >> 6, l = t & 63, lr = l & 15, lq = l >> 4;
  f4v acc[2][4] = {};
  const int arow = t >> 1, acol = (t & 1) * 16;
  const int brow = t >> 2, bcol = (t & 3) * 8;

  for (int k0 = 0; k0 < K; k0 += 32) {
    __syncthreads();
    *(s8v*)&As[arow][acol]     = *(const s8v*)&A[(size_t)(m0 + arow) * K + k0 + acol];
    *(s8v*)&As[arow][acol + 8] = *(const s8v*)&A[(size_t)(m0 + arow) * K + k0 + acol + 8];
    *(s8v*)&Bs[brow][bcol]     = *(const s8v*)&BT[(size_t)(n0 + brow) * K + k0 + bcol];
    __syncthreads();
    s8v a0 = *(const s8v*)&As[w * 32 + lr][lq * 8];
    s8v a1 = *(const s8v*)&As[w * 32 + 16 + lr][lq * 8];
#pragma unroll
    for (int ct = 0; ct < 4; ct++) {
      s8v bf = *(const s8v*)&Bs[ct * 16 + lr][lq * 8];
      acc[0][ct] = __builtin_amdgcn_mfma_f32_16x16x32_bf16(a0, bf, acc[0][ct], 0, 0, 0);
      acc[1][ct] = __builtin_amdgcn_mfma_f32_16x16x32_bf16(a1, bf, acc[1][ct], 0, 0, 0);
    }
  }
#pragma unroll
  for (int mt = 0; mt < 2; mt++)
#pragma unroll
    for (int ct = 0; ct < 4; ct++)
#pragma unroll
      for (int r = 0; r < 4; r++) {
        int row = m0 + w * 32 + mt * 16 + lq * 4 + r;
        const int col = n0 + ct * 16 + lr;
        if (kv_remap) row = (row >> 11) * KVROWS + (row & 2047) + 1;
        const float v = acc[mt][ct][r] * alpha;
        if constexpr (__is_same(OT, float)) C[(size_t)row * c_ld + col] = v;
        else                                C[(size_t)row * c_ld + col] = __float2bfloat16(v);
      }
}

// ---------------------------------------------------------------------------
// Fill kvbuf row 0 (null_kv, fp32->bf16) and tail rows 2049..2111 (zeros).
// ---------------------------------------------------------------------------
__global__ void fill_null_tail_kernel(const float* __restrict__ null_kv,
                                      bf16* __restrict__ kvbuf) {
  const int idx = blockIdx.x * 256 + threadIdx.x;  // [0, 4*64*64)
  const int d = idx & 63;
  const int s = (idx >> 6) & 63;
  const int b = idx >> 12;
  const int row = (s == 0) ? 0 : 2048 + s;
  kvbuf[(size_t)(b * KVROWS + row) * DHEAD + d] =
      (s == 0) ? __float2bfloat16(null_kv[d]) : __float2bfloat16(0.f);
}

// ---------------------------------------------------------------------------
// Flash-style causal attention, shared single-head KV + null token at col 0.
// Block = (b, h, 64-row q-tile); 4 waves x 16 q-rows. Online softmax in fp32.
// P: C-layout regs -> LDS -> A-layout (m120 pattern).
// ---------------------------------------------------------------------------
__global__ __launch_bounds__(256) void attn_kernel(
    const bf16* __restrict__ q,   // [B*SEQ][DIM]
    const bf16* __restrict__ kv,  // [B][KVROWS][64]
    bf16* __restrict__ o) {       // [B*SEQ][DIM]
  __shared__ bf16 kvs[64][64];     // 8 KB
  __shared__ bf16 Ps[4][16][64];   // 8 KB
  const int t = threadIdx.x, w = t >> 6, l = t & 63, lr = l & 15, lq = l >> 4;
  const int blk = blockIdx.x;
  const int qt = blk & 31, h = (blk >> 5) & 15, b = blk >> 9;
  const int q0 = qt * 64;

  const bf16* qrow = q + (size_t)(b * SEQ + q0 + w * 16 + lr) * DIM + h * DHEAD;
  const s8v qa0 = *(const s8v*)&qrow[lq * 8];
  const s8v qa1 = *(const s8v*)&qrow[32 + lq * 8];

  f4v oacc[4] = {};
  float m_i[4], l_i[4];
#pragma unroll
  for (int r = 0; r < 4; r++) { m_i[r] = -1e30f; l_i[r] = 0.f; }

  const bf16* kvb = kv + (size_t)b * KVROWS * DHEAD;
  const int jend = q0 + 65;
  const int srow = t >> 2, scol = (t & 3) * 16;

  for (int j0 = 0; j0 < jend; j0 += 64) {
    __syncthreads();
    *(s8v*)&kvs[srow][scol]     = *(const s8v*)&kvb[(size_t)(j0 + srow) * DHEAD + scol];
    *(s8v*)&kvs[srow][scol + 8] = *(const s8v*)&kvb[(size_t)(j0 + srow) * DHEAD + scol + 8];
    __syncthreads();

    f4v s[4];
#pragma unroll
    for (int ct = 0; ct < 4; ct++) {
      f4v z = {0.f, 0.f, 0.f, 0.f};
      s8v b0 = *(const s8v*)&kvs[ct * 16 + lr][lq * 8];
      s8v b1 = *(const s8v*)&kvs[ct * 16 + lr][32 + lq * 8];
      z = __builtin_amdgcn_mfma_f32_16x16x32_bf16(qa0, b0, z, 0, 0, 0);
      z = __builtin_amdgcn_mfma_f32_16x16x32_bf16(qa1, b1, z, 0, 0, 0);
      s[ct] = z;
    }

#pragma unroll
    for (int r = 0; r < 4; r++) {
      const int rowg = q0 + w * 16 + lq * 4 + r;
      float mx = -1e30f;
#pragma unroll
      for (int ct = 0; ct < 4; ct++) {
        const int colg = j0 + ct * 16 + lr;
        float v = (colg > rowg + 1) ? -1e30f : s[ct][r];
        s[ct][r] = v;
        mx = fmaxf(mx, v);
      }
      mx = fmaxf(mx, __shfl_xor(mx, 1));
      mx = fmaxf(mx, __shfl_xor(mx, 2));
      mx = fmaxf(mx, __shfl_xor(mx, 4));
      mx = fmaxf(mx, __shfl_xor(mx, 8));
      const float mnew = fmaxf(m_i[r], mx);
      const float alpha = __expf(m_i[r] - mnew);
      m_i[r] = mnew;
      float rs = 0.f;
#pragma unroll
      for (int ct = 0; ct < 4; ct++) {
        const float pv = __expf(s[ct][r] - mnew);
        s[ct][r] = pv;
        rs += pv;
      }
      rs += __shfl_xor(rs, 1);
      rs += __shfl_xor(rs, 2);
      rs += __shfl_xor(rs, 4);
      rs += __shfl_xor(rs, 8);
      l_i[r] = l_i[r] * alpha + rs;
#pragma unroll
      for (int ct = 0; ct < 4; ct++) oacc[ct][r] *= alpha;
    }

#pragma unroll
    for (int ct = 0; ct < 4; ct++)
#pragma unroll
      for (int r = 0; r < 4; r++)
        Ps[w][lq * 4 + r][ct * 16 + lr] = __float2bfloat16(s[ct][r]);
    __syncthreads();

    const s8v pa0 = *(const s8v*)&Ps[w][lr][lq * 8];
    const s8v pa1 = *(const s8v*)&Ps[w][lr][32 + lq * 8];
    const short* kvss = (const short*)kvs;
#pragma unroll
    for (int ct = 0; ct < 4; ct++) {
      s8v b0, b1;
#pragma unroll
      for (int j = 0; j < 8; j++) {
        b0[j] = kvss[(lq * 8 + j) * 64 + ct * 16 + lr];
        b1[j] = kvss[(32 + lq * 8 + j) * 64 + ct * 16 + lr];
      }
      oacc[ct] = __builtin_amdgcn_mfma_f32_16x16x32_bf16(pa0, b0, oacc[ct], 0, 0, 0);
      oacc[ct] = __builtin_amdgcn_mfma_f32_16x16x32_bf16(pa1, b1, oacc[ct], 0, 0, 0);
    }
  }

#pragma unroll
  for (int r = 0; r < 4; r++) {
    const int rowg = q0 + w * 16 + lq * 4 + r;
    const float inv = 1.0f / l_i[r];
#pragma unroll
    for (int ct = 0; ct < 4; ct++)
      o[(size_t)(b * SEQ + rowg) * DIM + h * DHEAD + ct * 16 + lr] =
          __float2bfloat16(oacc[ct][r] * inv);
  }
}

// ---------------------------------------------------------------------------
// Inputs are fp32 (per reference setup_inputs); output fp32 (32 MB in d_out).
// Workspace (~35.1 MB):
//   att   @ 0      16 MB bf16  (WqT@0, WkvT@+2MB alias it — dead before attn)
//   xb    @ 16 MB  16 MB bf16
//   WoutT @ 32 MB   2 MB bf16
//   kvbuf @ 34 MB   1.06 MB bf16
// q (bf16, 16 MB) lives in d_out; dead before final fp32 GEMM overwrites it.
// ---------------------------------------------------------------------------
extern "C" void kernel_launch(void* const* d_in, const int* in_sizes, int n_in,
                              void* d_out, int out_size, void* d_ws, size_t ws_size,
                              hipStream_t stream) {
  const float* x       = (const float*)d_in[0];  // [4,2048,1024]
  const float* Wq      = (const float*)d_in[1];  // [1024,1024]
  const float* Wkv     = (const float*)d_in[2];  // [1024,64]
  const float* null_kv = (const float*)d_in[3];  // [64]
  const float* Wout    = (const float*)d_in[4];  // [1024,1024]
  float* out = (float*)d_out;                    // [4,2048,1024] fp32

  bf16* q = (bf16*)d_out;                        // 16 MB staging inside d_out
  char* p = (char*)d_ws;
  bf16* att   = (bf16*)p;                                  // 16 MB
  bf16* xb    = (bf16*)(p + (size_t)16 * 1024 * 1024);     // 16 MB
  bf16* WoutT = (bf16*)(p + (size_t)32 * 1024 * 1024);     // 2 MB
  bf16* kvbuf = (bf16*)(p + (size_t)34 * 1024 * 1024);     // 1.06 MB
  bf16* WqT   = att;                                       // 2 MB (dead pre-attn)
  bf16* WkvT  = att + (size_t)DIM * DIM;                   // 128 KB (dead pre-attn)

  // x fp32 -> bf16 (8M elements, 8/thread)
  convert_kernel<<<(BATCH * SEQ * DIM) / (256 * 8), 256, 0, stream>>>(x, xb);

  const dim3 tb(32, 8);
  transpose_kernel<<<dim3(32, 32), tb, 0, stream>>>(Wq,   WqT,   DIM, DIM);
  transpose_kernel<<<dim3(2, 32),  tb, 0, stream>>>(Wkv,  WkvT,  DIM, DHEAD);
  transpose_kernel<<<dim3(32, 32), tb, 0, stream>>>(Wout, WoutT, DIM, DIM);

  // q = x @ Wq * DHEAD^-0.5 -> bf16 in d_out
  gemm_bt_kernel<bf16><<<dim3(64, 16), 256, 0, stream>>>(xb, WqT, q, DIM, DIM, 0.125f, 0);
  // kv = x @ Wkv -> kvbuf rows 1..2048 per batch (remapped epilogue)
  gemm_bt_kernel<bf16><<<dim3(64, 1), 256, 0, stream>>>(xb, WkvT, kvbuf, DIM, DHEAD, 1.0f, 1);
  fill_null_tail_kernel<<<(BATCH * 64 * 64) / 256, 256, 0, stream>>>(null_kv, kvbuf);
  // attention (overwrites WqT/WkvT region with att — both dead by now)
  attn_kernel<<<BATCH * HEADS * (SEQ / 64), 256, 0, stream>>>(q, kvbuf, att);
  // out = att @ Wout -> d_out fp32 (q dead)
  gemm_bt_kernel<float><<<dim3(64, 16), 256, 0, stream>>>(att, WoutT, out, DIM, DIM, 1.0f, 0);
}

// Round 4
// 279.627 us; speedup vs baseline: 1.8092x; 1.8092x over previous
//
#include <hip/hip_runtime.h>
#include <hip/hip_bf16.h>

#define HEADS  16
#define DHEAD  64
#define BATCH  4
#define SEQ    2048
#define DIM    1024
#define KVROWS 2112   // 2049 (null + SEQ) padded up to multiple of 64

typedef __hip_bfloat16 bf16;
typedef __attribute__((ext_vector_type(8))) short s8v;   // 8 x bf16 (4 VGPRs)
typedef __attribute__((ext_vector_type(4))) short s4v;   // 4 x bf16
typedef __attribute__((ext_vector_type(4))) float f4v;   // MFMA accumulator

// ---------------------------------------------------------------------------
// fp32 -> bf16 bulk convert (8 elements/thread)
// ---------------------------------------------------------------------------
__global__ void convert_kernel(const float* __restrict__ in, bf16* __restrict__ out) {
  const size_t i = ((size_t)blockIdx.x * 256 + threadIdx.x) * 8;
  const float4 a = *(const float4*)&in[i];
  const float4 b = *(const float4*)&in[i + 4];
  bf16 v[8] = {__float2bfloat16(a.x), __float2bfloat16(a.y),
               __float2bfloat16(a.z), __float2bfloat16(a.w),
               __float2bfloat16(b.x), __float2bfloat16(b.y),
               __float2bfloat16(b.z), __float2bfloat16(b.w)};
  *(s8v*)&out[i] = *(s8v*)v;
}

// ---------------------------------------------------------------------------
// Transpose+convert: fp32 [R][C] -> bf16 [C][R]; R,C multiples of 32
// ---------------------------------------------------------------------------
__global__ void transpose_kernel(const float* __restrict__ in, bf16* __restrict__ out,
                                 int R, int C) {
  __shared__ bf16 tile[32][33];
  const int c0 = blockIdx.x * 32, r0 = blockIdx.y * 32;
  const int tx = threadIdx.x, ty = threadIdx.y;
#pragma unroll
  for (int i = 0; i < 32; i += 8)
    tile[ty + i][tx] = __float2bfloat16(in[(size_t)(r0 + ty + i) * C + c0 + tx]);
  __syncthreads();
#pragma unroll
  for (int i = 0; i < 32; i += 8)
    out[(size_t)(c0 + ty + i) * R + r0 + tx] = tile[tx][ty + i];
}

// ---------------------------------------------------------------------------
// GEMM: C = alpha * A[M][K] @ BT[N][K]^T  (bf16 in, fp32 acc, OT out)
// Tile BM=128, BN=64, BK=32; 4 waves, MFMA 16x16x32 bf16.
// kv_remap: output row m -> kvbuf row (m>>11)*KVROWS + (m&2047)+1.
// ---------------------------------------------------------------------------
template <typename OT>
__global__ __launch_bounds__(256) void gemm_bt_kernel(
    const bf16* __restrict__ A, const bf16* __restrict__ BT,
    OT* __restrict__ C, int K, int c_ld, float alpha, int kv_remap) {
  __shared__ bf16 As[128][32];
  __shared__ bf16 Bs[64][32];
  const int m0 = blockIdx.x * 128, n0 = blockIdx.y * 64;
  const int t = threadIdx.x;
  const int w = t >> 6, l = t & 63, lr = l & 15, lq = l >> 4;
  f4v acc[2][4] = {};
  const int arow = t >> 1, acol = (t & 1) * 16;
  const int brow = t >> 2, bcol = (t & 3) * 8;

  for (int k0 = 0; k0 < K; k0 += 32) {
    __syncthreads();
    *(s8v*)&As[arow][acol]     = *(const s8v*)&A[(size_t)(m0 + arow) * K + k0 + acol];
    *(s8v*)&As[arow][acol + 8] = *(const s8v*)&A[(size_t)(m0 + arow) * K + k0 + acol + 8];
    *(s8v*)&Bs[brow][bcol]     = *(const s8v*)&BT[(size_t)(n0 + brow) * K + k0 + bcol];
    __syncthreads();
    s8v a0 = *(const s8v*)&As[w * 32 + lr][lq * 8];
    s8v a1 = *(const s8v*)&As[w * 32 + 16 + lr][lq * 8];
#pragma unroll
    for (int ct = 0; ct < 4; ct++) {
      s8v bf = *(const s8v*)&Bs[ct * 16 + lr][lq * 8];
      acc[0][ct] = __builtin_amdgcn_mfma_f32_16x16x32_bf16(a0, bf, acc[0][ct], 0, 0, 0);
      acc[1][ct] = __builtin_amdgcn_mfma_f32_16x16x32_bf16(a1, bf, acc[1][ct], 0, 0, 0);
    }
  }
#pragma unroll
  for (int mt = 0; mt < 2; mt++)
#pragma unroll
    for (int ct = 0; ct < 4; ct++)
#pragma unroll
      for (int r = 0; r < 4; r++) {
        int row = m0 + w * 32 + mt * 16 + lq * 4 + r;
        const int col = n0 + ct * 16 + lr;
        if (kv_remap) row = (row >> 11) * KVROWS + (row & 2047) + 1;
        const float v = acc[mt][ct][r] * alpha;
        if constexpr (__is_same(OT, float)) C[(size_t)row * c_ld + col] = v;
        else                                C[(size_t)row * c_ld + col] = __float2bfloat16(v);
      }
}

// ---------------------------------------------------------------------------
// Fill kvbuf row 0 (null_kv) and tail rows 2049..2111 (zeros).
// ---------------------------------------------------------------------------
__global__ void fill_null_tail_kernel(const float* __restrict__ null_kv,
                                      bf16* __restrict__ kvbuf) {
  const int idx = blockIdx.x * 256 + threadIdx.x;  // [0, 4*64*64)
  const int d = idx & 63;
  const int s = (idx >> 6) & 63;
  const int b = idx >> 12;
  const int row = (s == 0) ? 0 : 2048 + s;
  kvbuf[(size_t)(b * KVROWS + row) * DHEAD + d] =
      (s == 0) ? __float2bfloat16(null_kv[d]) : __float2bfloat16(0.f);
}

// ---------------------------------------------------------------------------
// Transposed flash attention: compute S^T = KV.Q^T and O^T = V^T.P^T so all
// LDS traffic in the loop is b128/b64 on 72-short-padded rows (no scalar
// gathers). Each lane owns exactly one q-row (i = lr) -> lane-uniform alpha,
// 2-shuffle reductions. q is pre-scaled by 0.125*log2(e); softmax uses exp2.
// Block = (b, h, 64-row q-tile), longest tiles dispatched first.
// ---------------------------------------------------------------------------
__global__ __launch_bounds__(256) void attn_kernel(
    const bf16* __restrict__ q,   // [B*SEQ][DIM] (pre-scaled)
    const bf16* __restrict__ kv,  // [B][KVROWS][64]
    bf16* __restrict__ o) {       // [B*SEQ][DIM]
  __shared__ bf16 kvs [64][72];   // kv[j][d], padded
  __shared__ bf16 kvsT[64][72];   // kv^T[d][j], padded
  __shared__ bf16 Ps[4][16][72];  // per-wave P^T as X[i][j] row-major
  const int t = threadIdx.x, w = t >> 6, l = t & 63, lr = l & 15, lq = l >> 4;
  const int blk = blockIdx.x;
  const int qt = 31 - (blk >> 6);          // longest q-tiles first
  const int hb = blk & 63, h = hb >> 2, b = hb & 3;
  const int q0 = qt * 64;
  const int iw = q0 + w * 16 + lr;         // this lane's q-row

  const bf16* qrow = q + ((size_t)(b * SEQ) + iw) * DIM + h * DHEAD;
  const s8v qb0 = *(const s8v*)&qrow[lq * 8];        // B-frag k=d 0..31
  const s8v qb1 = *(const s8v*)&qrow[32 + lq * 8];   // B-frag k=d 32..63

  f4v oaccT[4] = {};
  float m_i = -1e30f, l_i = 0.f;

  const bf16* kvb = kv + (size_t)b * KVROWS * DHEAD;
  const int jend = q0 + 65;
  const int srow = t >> 2, scol = (t & 3) * 16;

  for (int j0 = 0; j0 < jend; j0 += 64) {
    __syncthreads();  // prior iteration's kvs/kvsT readers done
    s8v r0 = *(const s8v*)&kvb[(size_t)(j0 + srow) * DHEAD + scol];
    s8v r1 = *(const s8v*)&kvb[(size_t)(j0 + srow) * DHEAD + scol + 8];
    *(s8v*)&kvs[srow][scol]     = r0;
    *(s8v*)&kvs[srow][scol + 8] = r1;
    const short* rr0 = (const short*)&r0;
    const short* rr1 = (const short*)&r1;
#pragma unroll
    for (int i2 = 0; i2 < 8; i2++) {
      ((short*)kvsT)[(scol + i2) * 72 + srow]     = rr0[i2];
      ((short*)kvsT)[(scol + 8 + i2) * 72 + srow] = rr1[i2];
    }
    __syncthreads();

    // S^T[j][i] = sum_d kv[j][d] * q[i][d]
    f4v st[4];
#pragma unroll
    for (int jt = 0; jt < 4; jt++) {
      f4v z = {0.f, 0.f, 0.f, 0.f};
      s8v a0 = *(const s8v*)&kvs[jt * 16 + lr][lq * 8];
      s8v a1 = *(const s8v*)&kvs[jt * 16 + lr][32 + lq * 8];
      z = __builtin_amdgcn_mfma_f32_16x16x32_bf16(a0, qb0, z, 0, 0, 0);
      z = __builtin_amdgcn_mfma_f32_16x16x32_bf16(a1, qb1, z, 0, 0, 0);
      st[jt] = z;  // C-layout: j = jt*16 + lq*4 + r, i = lr
    }

    // mask + online softmax (log2 domain)
    float mx = -1e30f;
#pragma unroll
    for (int jt = 0; jt < 4; jt++)
#pragma unroll
      for (int r = 0; r < 4; r++) {
        const int jg = j0 + jt * 16 + lq * 4 + r;
        float v = (jg > iw + 1) ? -1e30f : st[jt][r];
        st[jt][r] = v;
        mx = fmaxf(mx, v);
      }
    mx = fmaxf(mx, __shfl_xor(mx, 16));
    mx = fmaxf(mx, __shfl_xor(mx, 32));
    const float mnew = fmaxf(m_i, mx);
    const float alpha = exp2f(m_i - mnew);
    m_i = mnew;
    float rs = 0.f;
#pragma unroll
    for (int jt = 0; jt < 4; jt++)
#pragma unroll
      for (int r = 0; r < 4; r++) {
        const float pv = exp2f(st[jt][r] - mnew);
        st[jt][r] = pv;
        rs += pv;
      }
    rs += __shfl_xor(rs, 16);
    rs += __shfl_xor(rs, 32);
    l_i = l_i * alpha + rs;
#pragma unroll
    for (int dt = 0; dt < 4; dt++)
#pragma unroll
      for (int r = 0; r < 4; r++) oaccT[dt][r] *= alpha;

    // P^T -> Ps[w] (row i = lr, cols j), b64 writes (wave-local buffer)
#pragma unroll
    for (int jt = 0; jt < 4; jt++) {
      s4v pk;
#pragma unroll
      for (int r = 0; r < 4; r++) {
        bf16 h16 = __float2bfloat16(st[jt][r]);
        pk[r] = *(short*)&h16;
      }
      *(s4v*)&Ps[w][lr][jt * 16 + lq * 4] = pk;
    }

    // O^T[d][i] += sum_j kv^T[d][j] * P^T[j][i]
    const s8v pb0 = *(const s8v*)&Ps[w][lr][lq * 8];
    const s8v pb1 = *(const s8v*)&Ps[w][lr][32 + lq * 8];
#pragma unroll
    for (int dt = 0; dt < 4; dt++) {
      s8v a0 = *(const s8v*)&kvsT[dt * 16 + lr][lq * 8];
      s8v a1 = *(const s8v*)&kvsT[dt * 16 + lr][32 + lq * 8];
      oaccT[dt] = __builtin_amdgcn_mfma_f32_16x16x32_bf16(a0, pb0, oaccT[dt], 0, 0, 0);
      oaccT[dt] = __builtin_amdgcn_mfma_f32_16x16x32_bf16(a1, pb1, oaccT[dt], 0, 0, 0);
    }
  }

  // epilogue: O^T -> (wave-local LDS) -> coalesced O store
  const float inv = 1.0f / l_i;
#pragma unroll
  for (int dt = 0; dt < 4; dt++) {
    s4v pk;
#pragma unroll
    for (int r = 0; r < 4; r++) {
      bf16 h16 = __float2bfloat16(oaccT[dt][r] * inv);
      pk[r] = *(short*)&h16;
    }
    *(s4v*)&Ps[w][lr][dt * 16 + lq * 4] = pk;  // Ps[w][i][d] now holds O
  }
  const int orow = l >> 2, od = (l & 3) * 16;
  s8v o0 = *(const s8v*)&Ps[w][orow][od];
  s8v o1 = *(const s8v*)&Ps[w][orow][od + 8];
  bf16* op = o + ((size_t)(b * SEQ) + q0 + w * 16 + orow) * DIM + h * DHEAD + od;
  *(s8v*)&op[0] = o0;
  *(s8v*)&op[8] = o1;
}

// ---------------------------------------------------------------------------
// Inputs fp32, output fp32 (32 MB in d_out). Workspace ~35.1 MB:
//   att@0 16MB (WqT@0 + WkvT@+2MB alias it, dead pre-attn) | xb@16MB 16MB
//   WoutT@32MB 2MB | kvbuf@34MB 1.06MB.  q (bf16) staged inside d_out.
// ---------------------------------------------------------------------------
extern "C" void kernel_launch(void* const* d_in, const int* in_sizes, int n_in,
                              void* d_out, int out_size, void* d_ws, size_t ws_size,
                              hipStream_t stream) {
  const float* x       = (const float*)d_in[0];
  const float* Wq      = (const float*)d_in[1];
  const float* Wkv     = (const float*)d_in[2];
  const float* null_kv = (const float*)d_in[3];
  const float* Wout    = (const float*)d_in[4];
  float* out = (float*)d_out;

  bf16* q = (bf16*)d_out;  // 16 MB staging inside d_out (dead before final GEMM)
  char* p = (char*)d_ws;
  bf16* att   = (bf16*)p;
  bf16* xb    = (bf16*)(p + (size_t)16 * 1024 * 1024);
  bf16* WoutT = (bf16*)(p + (size_t)32 * 1024 * 1024);
  bf16* kvbuf = (bf16*)(p + (size_t)34 * 1024 * 1024);
  bf16* WqT   = att;
  bf16* WkvT  = att + (size_t)DIM * DIM;

  convert_kernel<<<(BATCH * SEQ * DIM) / (256 * 8), 256, 0, stream>>>(x, xb);

  const dim3 tb(32, 8);
  transpose_kernel<<<dim3(32, 32), tb, 0, stream>>>(Wq,   WqT,   DIM, DIM);
  transpose_kernel<<<dim3(2, 32),  tb, 0, stream>>>(Wkv,  WkvT,  DIM, DHEAD);
  transpose_kernel<<<dim3(32, 32), tb, 0, stream>>>(Wout, WoutT, DIM, DIM);

  // q = x @ Wq * (DHEAD^-0.5 * log2(e))  [log2-domain softmax]
  gemm_bt_kernel<bf16><<<dim3(64, 16), 256, 0, stream>>>(xb, WqT, q, DIM, DIM,
                                                         0.125f * 1.44269504089f, 0);
  gemm_bt_kernel<bf16><<<dim3(64, 1), 256, 0, stream>>>(xb, WkvT, kvbuf, DIM, DHEAD, 1.0f, 1);
  fill_null_tail_kernel<<<(BATCH * 64 * 64) / 256, 256, 0, stream>>>(null_kv, kvbuf);
  attn_kernel<<<BATCH * HEADS * (SEQ / 64), 256, 0, stream>>>(q, kvbuf, att);
  gemm_bt_kernel<float><<<dim3(64, 16), 256, 0, stream>>>(att, WoutT, out, DIM, DIM, 1.0f, 0);
}